// Round 3
// baseline (479.810 us; speedup 1.0000x reference)
//
#include <hip/hip_runtime.h>
#include <hip/hip_fp16.h>

#define Bb 4
#define Nn 20000
#define Ee 320000
#define CIN 32
#define COUT 32
#define Kk 16
#define Mm 2
#define EPB (Ee / 64)   /* direct path: 5000 super-iters (64 instances) per (b,m) slice */
#define WPB 1000        /* waves per (b,m) slice */

typedef __attribute__((ext_vector_type(8))) _Float16 half8;
typedef __attribute__((ext_vector_type(4))) float f32x4;

// ---------------- kernel 1: prep: transpose f -> fT (fp16); pack pb (fp16), pn; zero f_out (+cnt)
__global__ __launch_bounds__(256) void prep_fused(
    const float* __restrict__ f,
    const float4* __restrict__ bc4,
    const float4* __restrict__ bs4,
    const float* __restrict__ nodes,
    const float* __restrict__ nrm,
    __half* __restrict__ fT,          // [b][n][32] fp16
    float4* __restrict__ f_outz,      // fp16 accumulator viewed as float4 for zeroing
    __half* __restrict__ pb,          // [(b*2+m)][n][32] fp16: [bc 0..15 | bs 0..15]
    float4* __restrict__ pn,
    uint4* __restrict__ cntz) {       // 40000 uint4 (nullptr on direct path)
    __shared__ float ldsT[32 * 33];
    __shared__ float ldc[32 * 33];
    __shared__ float ldss[32 * 33];
    const int t   = threadIdx.x;
    const int blk = blockIdx.x;            // 2500 blocks
    const int b   = blk / 625;
    const int n0  = (blk % 625) * 32;
    {
        int lane = t & 31, grp = t >> 5;
        #pragma unroll
        for (int r = 0; r < 4; ++r)
            ldsT[(grp + r * 8) * 33 + lane] = f[(b * CIN + grp + r * 8) * Nn + n0 + lane];
        __syncthreads();
        int nl = t >> 3, c4 = (t & 7) * 4;
        union { short4 s4; __half h[4]; } u;
        #pragma unroll
        for (int j = 0; j < 4; ++j)
            u.h[j] = __float2half(ldsT[(c4 + j) * 33 + nl]);
        *(short4*)(fT + ((size_t)(b * Nn) + n0 + nl) * CIN + c4) = u.s4;
    }
    {
        int nl = t >> 3, j4 = t & 7;
        float4 vc = bc4[(b * Nn + n0 + nl) * 8 + j4];
        float4 vs = bs4[(b * Nn + n0 + nl) * 8 + j4];
        float* pc = ldc + nl * 33 + 4 * j4;
        pc[0] = vc.x; pc[1] = vc.y; pc[2] = vc.z; pc[3] = vc.w;
        float* ps = ldss + nl * 33 + 4 * j4;
        ps[0] = vs.x; ps[1] = vs.y; ps[2] = vs.z; ps[3] = vs.w;
        __syncthreads();
        int m = (t >> 2) & 1, chunk = t & 3;
        const float* src = (chunk < 2 ? ldc : ldss) + nl * 33;
        int k0 = (chunk & 1) * 8;
        union { float4 v; __half h[8]; } o;
        #pragma unroll
        for (int j = 0; j < 8; ++j)
            o.h[j] = __float2half(src[2 * (k0 + j) + m]);
        ((float4*)pb)[(((size_t)(b * 2 + m)) * Nn + n0 + nl) * 4 + chunk] = o.v;
    }
    const int t0 = blk * 256 + t, S = 2500 * 256;
    for (int i = t0; i < 320000; i += S) f_outz[i] = make_float4(0, 0, 0, 0);
    if (cntz)
        for (int i = t0; i < 40000; i += S) cntz[i] = make_uint4(0, 0, 0, 0);
    for (int i = t0; i < Bb * Nn; i += S) {
        float2 nd = ((const float2*)nodes)[i];
        float2 nv = ((const float2*)nrm)[i];
        pn[i] = make_float4(nd.x, nd.y, nv.x, nv.y);
    }
}

// ---------------- kernel 2 (sorted path): histogram of targets per (b,m) slice
__global__ __launch_bounds__(256) void hist_kernel(
    const int4* __restrict__ de4, unsigned* __restrict__ cnt) {
    int i = blockIdx.x * 256 + threadIdx.x;     // 0 .. B*Ee-1 (grid 5000*256 exact)
    int b = i / Ee;
    int4 d4 = de4[i];
    atomicAdd(&cnt[(b * 2 + 0) * Nn + d4.x], 1u);
    atomicAdd(&cnt[(b * 2 + 1) * Nn + d4.y], 1u);
}

// ---------------- kernel 3 (sorted path): exclusive scan of 20000 counters per slice
__global__ __launch_bounds__(256) void scan_kernel(unsigned* __restrict__ cnt) {
    __shared__ unsigned part[256];
    unsigned* cc = cnt + blockIdx.x * Nn;
    const int t  = threadIdx.x;
    const int i0 = t * 79;
    const int i1 = (i0 + 79 < Nn) ? i0 + 79 : Nn;
    unsigned s = 0;
    for (int i = i0; i < i1; ++i) s += cc[i];
    part[t] = s;
    __syncthreads();
    for (int d = 1; d < 256; d <<= 1) {
        unsigned v = (t >= d) ? part[t - d] : 0u;
        __syncthreads();
        part[t] += v;
        __syncthreads();
    }
    unsigned run = t ? part[t - 1] : 0u;
    for (int i = i0; i < i1; ++i) { unsigned v = cc[i]; cc[i] = run; run += v; }
}

// ---------------- kernel 4 (sorted path): recompute geometry, scatter sorted records
// record: x = tgt | (src<<15), y = bits(scale)
__global__ __launch_bounds__(256) void scatter_geom(
    const int4* __restrict__ de4,
    const float4* __restrict__ pn,
    const float2* __restrict__ nwt2,
    unsigned* __restrict__ cnt,
    uint2* __restrict__ srec) {
    int i = blockIdx.x * 256 + threadIdx.x;     // 0 .. B*Ee-1
    int b = i / Ee;
    int4 d4 = de4[i];
    float2 nw = nwt2[i];
    #pragma unroll
    for (int m = 0; m < 2; ++m) {
        int tn = m ? d4.y : d4.x;
        int sn = m ? d4.w : d4.z;
        float4 qt = pn[b * Nn + tn];
        float4 qs = pn[b * Nn + sn];
        float dx = qt.x - qs.x, dy = qt.y - qs.y;
        float r2 = dx * dx + dy * dy + 1e-6f;
        float sc = (m ? nw.y : nw.x) * (dx * qs.z + dy * qs.w) / r2;
        unsigned slot = atomicAdd(&cnt[(b * 2 + m) * Nn + tn], 1u);
        srec[(size_t)(b * 2 + m) * Ee + slot] =
            make_uint2((unsigned)tn | ((unsigned)sn << 15), __float_as_uint(sc));
    }
}

// ---------------- kernel 5a (sorted): edge MFMA matvec over sorted records, run-merged atomics
__global__ __launch_bounds__(256, 4) void edge_sorted(
    const float4* __restrict__ pbh4,   // pb fp16 viewed as float4 (4 chunks/row)
    const __half* __restrict__ fTh,
    const uint2* __restrict__ srec,
    const float* __restrict__ wc,
    const float* __restrict__ wsp,
    const float* __restrict__ w0,
    __half* __restrict__ f_out) {
    __shared__ __align__(16) __half spb[4][16 * 64];   // 8192 B
    const int t  = threadIdx.x;
    const int wv = t >> 6;
    const int l  = t & 63;
    const int c  = l & 15;
    const int q  = l >> 4;
    const int mode = q >> 1;
    const unsigned smask2 = mode ? 0x80008000u : 0u;
    const int bm = blockIdx.x & 7;                 // slice = b*2+m (XCD-pinned)
    const int b  = bm >> 1, m = bm & 1;
    const int wid = (blockIdx.x >> 3) * 4 + wv;    // 0..999
    const uint2* rbase = srec + (size_t)bm * Ee + wid * 320;
    const int pbbase = bm * Nn;
    const int fbase  = b * Nn;

    // loop-invariant B fragments (weights, fp16): B[k=q*8+j][ch]
    half8 bf0, bf1;
    #pragma unroll
    for (int j = 0; j < 8; ++j) {
        int k = q * 8 + j;
        float w0v, w1v;
        if (k < 16) {
            w0v = 2.0f * wc[(c * Kk + k) * Mm + m];
            w1v = 2.0f * wc[((c + 16) * Kk + k) * Mm + m];
        } else {
            w0v = 2.0f * wsp[(c * Kk + (k - 16)) * Mm + m];
            w1v = 2.0f * wsp[((c + 16) * Kk + (k - 16)) * Mm + m];
        }
        bf0[j] = (_Float16)w0v;
        bf1[j] = (_Float16)w1v;
    }
    const float acc00 = w0[c * Mm + m] + 1.0f;
    const float acc01 = w0[(c + 16) * Mm + m] + 1.0f;

    __half* myld = spb[wv];
    const int il = l >> 2, jj4 = l & 3;
    // LDS addresses: phys chunk = logical ^ (row & 7) -> conflict-free b128
    float4* wT = (float4*)(myld + il * 64 + 8 * (jj4 ^ (il & 7)));
    float4* wS = (float4*)(myld + il * 64 + 8 * ((4 | jj4) ^ (il & 7)));
    const int cs = c & 7;
    const float4* rBC = (const float4*)(myld + c * 64 + 8 * ((q & 1) ^ cs));
    const float4* rBS = (const float4*)(myld + c * 64 + 8 * ((2 | (q & 1)) ^ cs));
    const float4* rXX = (const float4*)(myld + c * 64 + 8 * ((4 | q) ^ cs));
    const float4* rYY = (const float4*)(myld + c * 64 + 8 * ((4 | (q ^ 2)) ^ cs));

    const int ceven = ((c & 1) == 0);
    const int choff = ceven ? c : (c + 15);        // pk-atomic halfword offset

    // run-merge state (fp32 accumulation, flush on target change)
    int cur_row = -1;
    float a0 = 0.f, a1 = 0.f;

    // lane l holds record rq*80 + it*16 + ri of this wave's 320-edge range
    const int rq = l >> 4, ri = l & 15;
    uint2 rc = rbase[rq * 80 + ri];
    float scf = __uint_as_float(rc.y);

    float4 g0, g2;
    float fa[4], fb[4];
    {   // prologue prefetch for (it=0, tau=0)
        int srcR = ((il >> 2) << 4) + (il & 3);
        unsigned px = (unsigned)__shfl((int)rc.x, srcR);
        int tn = px & 32767, sn = (px >> 15) & 32767;
        g0 = pbh4[(size_t)(pbbase + tn) * 4 + jj4];
        g2 = pbh4[(size_t)(pbbase + sn) * 4 + jj4];
        #pragma unroll
        for (int r = 0; r < 4; ++r) {
            unsigned pf = (unsigned)__shfl((int)rc.x, (q << 4) + r);
            int sr = (pf >> 15) & 32767;
            fa[r] = __half2float(fTh[(size_t)(fbase + sr) * CIN + c]);
            fb[r] = __half2float(fTh[(size_t)(fbase + sr) * CIN + c + 16]);
        }
    }

    uint2 rn;
    for (int it = 0; it < 5; ++it) {
        const bool lastit = (it == 4);
        if (!lastit) rn = rbase[rq * 80 + (it + 1) * 16 + ri];
        #pragma unroll
        for (int tau = 0; tau < 4; ++tau) {
            // ---- 1. commit prefetched pb rows to LDS (swizzled)
            *wT = g0;
            *wS = g2;

            // ---- 2. A-frag: fp16 LDS reads + pk-fp16 math + fp16 MFMA
            union { float4 v; unsigned u[4]; } ubc, ubs, uxx, uyy;
            ubc.v = *rBC; ubs.v = *rBS; uxx.v = *rXX; uyy.v = *rYY;
            union { half8 h8; unsigned u[4]; } af;
            #pragma unroll
            for (int jp = 0; jp < 4; ++jp) {
                unsigned bsbits = ubs.u[jp] ^ smask2;
                __half2 hb = *(__half2*)&ubc.u[jp];
                __half2 hs = *(__half2*)&bsbits;
                __half2 hx = *(__half2*)&uxx.u[jp];
                __half2 hy = *(__half2*)&uyy.u[jp];
                __half2 v  = __hfma2(hb, hx, __hmul2(hs, hy));
                af.u[jp] = *(unsigned*)&v;
            }
            f32x4 zero = {0.f, 0.f, 0.f, 0.f};
            f32x4 d0 = __builtin_amdgcn_mfma_f32_16x16x32_f16(af.h8, bf0, zero, 0, 0, 0);
            f32x4 d1 = __builtin_amdgcn_mfma_f32_16x16x32_f16(af.h8, bf1, zero, 0, 0, 0);

            // ---- 3. epilogue + run-merge (each q-group walks its 80 edges in sorted order)
            #pragma unroll
            for (int r = 0; r < 4; ++r) {
                int srcl = (q << 4) + (tau << 2) + r;
                float sc = __shfl(scf, srcl);
                int row  = (unsigned)__shfl((int)rc.x, srcl) & 32767;
                float v0 = (acc00 + d0[r]) * fa[r] * sc;
                float v1 = (acc01 + d1[r]) * fb[r] * sc;
                // predicate uniform across the 16 c-lanes of this q-group,
                // so the (c, c^1) pk-pair always branches together
                if (row != cur_row) {
                    if (cur_row >= 0) {
                        float n0 = __shfl_xor(a0, 1);
                        float n1 = __shfl_xor(a1, 1);
                        __half2 hv = ceven ? __floats2half2_rn(a0, n0)
                                           : __floats2half2_rn(n1, a1);
                        unsafeAtomicAdd((__half2*)(f_out +
                            (size_t)(fbase + cur_row) * CIN + choff), hv);
                    }
                    cur_row = row; a0 = v0; a1 = v1;
                } else {
                    a0 += v0; a1 += v1;
                }
            }

            // ---- 4. prefetch next tau (pb rows + fT)
            if (tau < 3 || !lastit) {
                const int ntau = (tau == 3) ? 0 : tau + 1;
                const unsigned bx = (tau == 3) ? rn.x : rc.x;
                int srcR = ((il >> 2) << 4) + (ntau << 2) + (il & 3);
                unsigned px = (unsigned)__shfl((int)bx, srcR);
                int tn = px & 32767, sn = (px >> 15) & 32767;
                g0 = pbh4[(size_t)(pbbase + tn) * 4 + jj4];
                g2 = pbh4[(size_t)(pbbase + sn) * 4 + jj4];
                #pragma unroll
                for (int r = 0; r < 4; ++r) {
                    unsigned pf = (unsigned)__shfl((int)bx, (q << 4) + (ntau << 2) + r);
                    int sr = (pf >> 15) & 32767;
                    fa[r] = __half2float(fTh[(size_t)(fbase + sr) * CIN + c]);
                    fb[r] = __half2float(fTh[(size_t)(fbase + sr) * CIN + c + 16]);
                }
            }
        }
        if (!lastit) { rc = rn; scf = __uint_as_float(rc.y); }
    }
    // ---- final flush (cur_row valid: every lane processed 80 edges)
    {
        float n0 = __shfl_xor(a0, 1);
        float n1 = __shfl_xor(a1, 1);
        __half2 hv = ceven ? __floats2half2_rn(a0, n0)
                           : __floats2half2_rn(n1, a1);
        unsafeAtomicAdd((__half2*)(f_out + (size_t)(fbase + cur_row) * CIN + choff), hv);
    }
}

// ---------------- kernel 5b (direct, harness-verified fallback): unsorted edge scatter
__global__ __launch_bounds__(256, 4) void edge_direct(
    const float4* __restrict__ pbh4,
    const float4* __restrict__ pn,
    const __half* __restrict__ fTh,
    const int4* __restrict__ de4,
    const float* __restrict__ nwt,
    const float* __restrict__ wc,
    const float* __restrict__ wsp,
    const float* __restrict__ w0,
    __half* __restrict__ f_out) {
    __shared__ __align__(16) __half spb[4][16 * 64];
    const int t  = threadIdx.x;
    const int wv = t >> 6;
    const int l  = t & 63;
    const int c  = l & 15;
    const int q  = l >> 4;
    const int mode = q >> 1;
    const unsigned smask2 = mode ? 0x80008000u : 0u;
    const int bm = blockIdx.x & 7;
    const int b  = bm >> 1, m = bm & 1;
    const int wid = (blockIdx.x >> 3) * 4 + wv;
    const int rowoff = (b + m) * Nn;

    half8 bf0, bf1;
    #pragma unroll
    for (int j = 0; j < 8; ++j) {
        int k = q * 8 + j;
        float w0v, w1v;
        if (k < 16) {
            w0v = 2.0f * wc[(c * Kk + k) * Mm + m];
            w1v = 2.0f * wc[((c + 16) * Kk + k) * Mm + m];
        } else {
            w0v = 2.0f * wsp[(c * Kk + (k - 16)) * Mm + m];
            w1v = 2.0f * wsp[((c + 16) * Kk + (k - 16)) * Mm + m];
        }
        bf0[j] = (_Float16)w0v;
        bf1[j] = (_Float16)w1v;
    }
    const float acc00 = w0[c * Mm + m] + 1.0f;
    const float acc01 = w0[(c + 16) * Mm + m] + 1.0f;

    __half* myld = spb[wv];
    const int il = l >> 2, jj4 = l & 3;
    float4* wT = (float4*)(myld + il * 64 + 8 * (jj4 ^ (il & 7)));
    float4* wS = (float4*)(myld + il * 64 + 8 * ((4 | jj4) ^ (il & 7)));
    const int cs = c & 7;
    const float4* rBC = (const float4*)(myld + c * 64 + 8 * ((q & 1) ^ cs));
    const float4* rBS = (const float4*)(myld + c * 64 + 8 * ((2 | (q & 1)) ^ cs));
    const float4* rXX = (const float4*)(myld + c * 64 + 8 * ((4 | q) ^ cs));
    const float4* rYY = (const float4*)(myld + c * 64 + 8 * ((4 | (q ^ 2)) ^ cs));
    const int ceven = ((c & 1) == 0);
    const int choff = ceven ? c : (c + 15);

    float scale; int bt, bs;
    float4 g0, g2;
    float fa[4], fb[4];
    int4  d4n;
    int   btn, bsn;
    float dxn, dyn, nzn, nwn2, nwn;

    int s = wid;
    {
        int e = s * 64 + l;
        int4 d4 = de4[b * Ee + e];
        int tn = m ? d4.y : d4.x;
        int sn = m ? d4.w : d4.z;
        bt = b * Nn + tn;
        bs = b * Nn + sn;
        float4 qt = pn[bt];
        float4 qs = pn[bs];
        float dx = qt.x - qs.x, dy = qt.y - qs.y;
        float r2 = dx * dx + dy * dy + 1e-6f;
        scale = nwt[(b * Ee + e) * Mm + m] * (dx * qs.z + dy * qs.w) / r2;
        int bta = __shfl(bt, il), bsa = __shfl(bs, il);
        g0 = pbh4[(bta + rowoff) * 4 + jj4];
        g2 = pbh4[(bsa + rowoff) * 4 + jj4];
        #pragma unroll
        for (int r = 0; r < 4; ++r) {
            int bsr = __shfl(bs, 4 * q + r);
            fa[r] = __half2float(fTh[bsr * CIN + c]);
            fb[r] = __half2float(fTh[bsr * CIN + c + 16]);
        }
    }

    for (; s < EPB; s += WPB) {
        const bool last = (s + WPB >= EPB);
        #pragma unroll
        for (int tau = 0; tau < 4; ++tau) {
            *wT = g0;
            *wS = g2;
            union { float4 v; unsigned u[4]; } ubc, ubs, uxx, uyy;
            ubc.v = *rBC; ubs.v = *rBS; uxx.v = *rXX; uyy.v = *rYY;
            union { half8 h8; unsigned u[4]; } af;
            #pragma unroll
            for (int jp = 0; jp < 4; ++jp) {
                unsigned bsbits = ubs.u[jp] ^ smask2;
                __half2 hb = *(__half2*)&ubc.u[jp];
                __half2 hs = *(__half2*)&bsbits;
                __half2 hx = *(__half2*)&uxx.u[jp];
                __half2 hy = *(__half2*)&uyy.u[jp];
                __half2 v  = __hfma2(hb, hx, __hmul2(hs, hy));
                af.u[jp] = *(unsigned*)&v;
            }
            f32x4 zero = {0.f, 0.f, 0.f, 0.f};
            f32x4 d0 = __builtin_amdgcn_mfma_f32_16x16x32_f16(af.h8, bf0, zero, 0, 0, 0);
            f32x4 d1 = __builtin_amdgcn_mfma_f32_16x16x32_f16(af.h8, bf1, zero, 0, 0, 0);

            float val0[4], val1[4];
            int   btr[4];
            #pragma unroll
            for (int r = 0; r < 4; ++r) {
                int srcl = tau * 16 + 4 * q + r;
                float sc = __shfl(scale, srcl);
                btr[r]   = __shfl(bt, srcl);
                val0[r] = (acc00 + d0[r]) * fa[r] * sc;
                val1[r] = (acc01 + d1[r]) * fb[r] * sc;
            }

            if (tau == 1 && !last)
                d4n = de4[b * Ee + (s + WPB) * 64 + l];
            if (tau == 2 && !last) {
                int tn = m ? d4n.y : d4n.x;
                int sn = m ? d4n.w : d4n.z;
                btn = b * Nn + tn;
                bsn = b * Nn + sn;
                float4 qt = pn[btn];
                float4 qs = pn[bsn];
                dxn = qt.x - qs.x; dyn = qt.y - qs.y;
                nzn = qs.z; nwn2 = qs.w;
                nwn = nwt[(b * Ee + (s + WPB) * 64 + l) * Mm + m];
            }

            if (tau < 3 || !last) {
                int ntau;
                if (tau == 3) {
                    float r2 = dxn * dxn + dyn * dyn + 1e-6f;
                    scale = nwn * (dxn * nzn + dyn * nwn2) / r2;
                    bt = btn; bs = bsn;
                    ntau = 0;
                } else {
                    ntau = tau + 1;
                }
                int srcA = ntau * 16 + il;
                int bta = __shfl(bt, srcA), bsa = __shfl(bs, srcA);
                g0 = pbh4[(bta + rowoff) * 4 + jj4];
                g2 = pbh4[(bsa + rowoff) * 4 + jj4];
                #pragma unroll
                for (int r = 0; r < 4; ++r) {
                    int bsr = __shfl(bs, ntau * 16 + 4 * q + r);
                    fa[r] = __half2float(fTh[bsr * CIN + c]);
                    fb[r] = __half2float(fTh[bsr * CIN + c + 16]);
                }
            }

            __builtin_amdgcn_sched_barrier(0);
            #pragma unroll
            for (int r = 0; r < 4; ++r) {
                float n0 = __shfl_xor(val0[r], 1);
                float n1 = __shfl_xor(val1[r], 1);
                __half2 hv = ceven ? __floats2half2_rn(val0[r], n0)
                                   : __floats2half2_rn(n1, val1[r]);
                unsafeAtomicAdd((__half2*)(f_out + (size_t)btr[r] * CIN + choff), hv);
            }
        }
    }
}

// ---------------- kernel 6: out[b,o,n] = bias[o] + sum_i wk[o,i] * f_out[b,n,i]
__global__ __launch_bounds__(256) void out_kernel(
    const float4* __restrict__ f_out4,    // fp16 data viewed as float4 (8 halves)
    const float* __restrict__ wk,
    const float* __restrict__ bias,
    float* __restrict__ out) {
    __shared__ float lwk[1024];
    __shared__ float lf[64 * 33];
    int blk  = blockIdx.x;
    int b    = blk / 313;
    int tile = blk % 313;
    int n0   = tile * 64;
    int t    = threadIdx.x;
    #pragma unroll
    for (int r = 0; r < 4; ++r) lwk[r * 256 + t] = wk[r * 256 + t];
    {
        int nl = t >> 2, i8 = t & 3;
        int n  = n0 + nl;
        union { float4 v; __half2 h[4]; } u;
        u.v = (n < Nn) ? f_out4[((size_t)b * Nn + n) * 4 + i8]
                       : make_float4(0, 0, 0, 0);
        float* p = lf + nl * 33 + i8 * 8;
        #pragma unroll
        for (int j = 0; j < 4; ++j) {
            float2 fj = __half22float2(u.h[j]);
            p[2 * j]     = fj.x;
            p[2 * j + 1] = fj.y;
        }
    }
    __syncthreads();
    int nl = t & 63;
    int og = t >> 6;
    int n  = n0 + nl;
    if (n < Nn) {
        #pragma unroll
        for (int r = 0; r < 8; ++r) {
            int o = r * 4 + og;
            float acc = bias[o];
            #pragma unroll
            for (int i = 0; i < 32; ++i) acc += lwk[o * 32 + i] * lf[nl * 33 + i];
            out[(b * COUT + o) * Nn + n] = acc;
        }
    }
}

extern "C" void kernel_launch(void* const* d_in, const int* in_sizes, int n_in,
                              void* d_out, int out_size, void* d_ws, size_t ws_size,
                              hipStream_t stream) {
    const float* f       = (const float*)d_in[0];
    const float* bases_c = (const float*)d_in[1];
    const float* bases_s = (const float*)d_in[2];
    const float* nodes   = (const float*)d_in[4];
    const float* nrm     = (const float*)d_in[5];
    const int*   de      = (const int*)d_in[6];
    const float* nwt     = (const float*)d_in[7];
    const float* wc      = (const float*)d_in[8];
    const float* wsp     = (const float*)d_in[9];
    const float* w0      = (const float*)d_in[10];
    const float* wk      = (const float*)d_in[11];
    const float* bias    = (const float*)d_in[12];
    float* out = (float*)d_out;

    __half*   fT    = (__half*)d_ws;                           // 5.12 MB
    __half*   pb    = fT + 2560000;                            // 10.24 MB
    float4*   pn    = (float4*)(pb + 5120000);                 // 1.28 MB
    __half*   f_out = (__half*)(pn + 80000);                   // 5.12 MB  (ends 21.76 MB)
    unsigned* cnt   = (unsigned*)(f_out + 2560000);            // 0.64 MB
    uint2*    srec  = (uint2*)(cnt + 160000);                  // 20.48 MB (ends 42.88 MB)

    const bool sorted = (ws_size >= (size_t)42880000);

    prep_fused<<<2500, 256, 0, stream>>>(f, (const float4*)bases_c,
                                         (const float4*)bases_s, nodes, nrm,
                                         fT, (float4*)f_out, pb, pn,
                                         sorted ? (uint4*)cnt : (uint4*)nullptr);
    if (sorted) {
        hist_kernel<<<5000, 256, 0, stream>>>((const int4*)de, cnt);
        scan_kernel<<<8, 256, 0, stream>>>(cnt);
        scatter_geom<<<5000, 256, 0, stream>>>((const int4*)de, pn,
                                               (const float2*)nwt, cnt, srec);
        edge_sorted<<<2000, 256, 0, stream>>>((const float4*)pb, fT, srec,
                                              wc, wsp, w0, f_out);
    } else {
        edge_direct<<<2000, 256, 0, stream>>>((const float4*)pb, pn, fT,
                                              (const int4*)de, nwt, wc, wsp, w0, f_out);
    }
    out_kernel<<<Bb * 313, 256, 0, stream>>>((const float4*)f_out, wk, bias, out);
}

// Round 4
// 427.136 us; speedup vs baseline: 1.1233x; 1.1233x over previous
//
#include <hip/hip_runtime.h>
#include <hip/hip_fp16.h>

#define Bb 4
#define Nn 20000
#define Ee 320000
#define CIN 32
#define COUT 32
#define Kk 16
#define Mm 2
#define EPB (Ee / 64)   /* direct path: 5000 super-iters (64 instances) per (b,m) slice */
#define WPB 1000        /* waves per (b,m) slice */

typedef __attribute__((ext_vector_type(8))) _Float16 half8;
typedef __attribute__((ext_vector_type(4))) float f32x4;
typedef __attribute__((ext_vector_type(4))) int   i32x4;
typedef __attribute__((ext_vector_type(2))) int   i32x2;
typedef __attribute__((ext_vector_type(2))) float f32x2;
typedef __attribute__((ext_vector_type(2))) unsigned u32x2;

// ---------------- kernel 1: prep: transpose f -> fT (fp16); pack pb (fp16), pn; zero f_out (+cnt)
__global__ __launch_bounds__(256) void prep_fused(
    const float* __restrict__ f,
    const float4* __restrict__ bc4,
    const float4* __restrict__ bs4,
    const float* __restrict__ nodes,
    const float* __restrict__ nrm,
    __half* __restrict__ fT,          // [b][n][32] fp16
    float4* __restrict__ f_outz,      // fp16 accumulator viewed as float4 for zeroing
    __half* __restrict__ pb,          // [(b*2+m)][n][32] fp16: [bc 0..15 | bs 0..15]
    float4* __restrict__ pn,
    uint4* __restrict__ cntz) {       // 40000 uint4 (nullptr on direct path)
    __shared__ float ldsT[32 * 33];
    __shared__ float ldc[32 * 33];
    __shared__ float ldss[32 * 33];
    const int t   = threadIdx.x;
    const int blk = blockIdx.x;            // 2500 blocks
    const int b   = blk / 625;
    const int n0  = (blk % 625) * 32;
    {
        int lane = t & 31, grp = t >> 5;
        #pragma unroll
        for (int r = 0; r < 4; ++r)
            ldsT[(grp + r * 8) * 33 + lane] = f[(b * CIN + grp + r * 8) * Nn + n0 + lane];
        __syncthreads();
        int nl = t >> 3, c4 = (t & 7) * 4;
        union { short4 s4; __half h[4]; } u;
        #pragma unroll
        for (int j = 0; j < 4; ++j)
            u.h[j] = __float2half(ldsT[(c4 + j) * 33 + nl]);
        *(short4*)(fT + ((size_t)(b * Nn) + n0 + nl) * CIN + c4) = u.s4;
    }
    {
        int nl = t >> 3, j4 = t & 7;
        float4 vc = bc4[(b * Nn + n0 + nl) * 8 + j4];
        float4 vs = bs4[(b * Nn + n0 + nl) * 8 + j4];
        float* pc = ldc + nl * 33 + 4 * j4;
        pc[0] = vc.x; pc[1] = vc.y; pc[2] = vc.z; pc[3] = vc.w;
        float* ps = ldss + nl * 33 + 4 * j4;
        ps[0] = vs.x; ps[1] = vs.y; ps[2] = vs.z; ps[3] = vs.w;
        __syncthreads();
        int m = (t >> 2) & 1, chunk = t & 3;
        const float* src = (chunk < 2 ? ldc : ldss) + nl * 33;
        int k0 = (chunk & 1) * 8;
        union { float4 v; __half h[8]; } o;
        #pragma unroll
        for (int j = 0; j < 8; ++j)
            o.h[j] = __float2half(src[2 * (k0 + j) + m]);
        ((float4*)pb)[(((size_t)(b * 2 + m)) * Nn + n0 + nl) * 4 + chunk] = o.v;
    }
    const int t0 = blk * 256 + t, S = 2500 * 256;
    for (int i = t0; i < 320000; i += S) f_outz[i] = make_float4(0, 0, 0, 0);
    if (cntz)
        for (int i = t0; i < 40000; i += S) cntz[i] = make_uint4(0, 0, 0, 0);
    for (int i = t0; i < Bb * Nn; i += S) {
        float2 nd = ((const float2*)nodes)[i];
        float2 nv = ((const float2*)nrm)[i];
        pn[i] = make_float4(nd.x, nd.y, nv.x, nv.y);
    }
}

// ---------------- kernel 2 (sorted): per-slice target histogram, XCD-pinned by blockIdx&7
__global__ __launch_bounds__(256) void hist_kernel(
    const int* __restrict__ de, unsigned* __restrict__ cnt) {
    const int bm = blockIdx.x & 7;                 // slice (XCD-pinned)
    const int b  = bm >> 1, m = bm & 1;
    const int tid = (blockIdx.x >> 3) * 256 + threadIdx.x;   // 0..65535
    unsigned* cc = cnt + bm * Nn;                  // 80 KB, L2-resident on this XCD
    const i32x2* tg = (const i32x2*)de;            // int2 #2i = {t_m0, t_m1} of edge i
    for (int e = tid; e < Ee; e += 65536) {
        i32x2 d2 = __builtin_nontemporal_load(&tg[(size_t)(b * Ee + e) * 2]);
        int tn = m ? d2.y : d2.x;
        atomicAdd(&cc[tn], 1u);
    }
}

// ---------------- kernel 3 (sorted): exclusive scan of 20000 counters per slice
__global__ __launch_bounds__(1024) void scan_kernel(unsigned* __restrict__ cnt) {
    __shared__ unsigned part[1024];
    unsigned* cc = cnt + blockIdx.x * Nn;
    const int t  = threadIdx.x;
    const int i0 = t * 20;
    const int i1 = (i0 + 20 < Nn) ? i0 + 20 : Nn;
    unsigned s = 0;
    for (int i = i0; i < i1; ++i) s += cc[i];
    part[t] = s;
    __syncthreads();
    for (int d = 1; d < 1024; d <<= 1) {
        unsigned v = (t >= d) ? part[t - d] : 0u;
        __syncthreads();
        part[t] += v;
        __syncthreads();
    }
    unsigned run = t ? part[t - 1] : 0u;
    for (int i = i0; i < i1; ++i) { unsigned v = cc[i]; cc[i] = run; run += v; }
}

// ---------------- kernel 4 (sorted): geometry + record scatter, XCD-pinned by blockIdx&7
// record: x = tgt | (src<<15), y = bits(scale)
__global__ __launch_bounds__(256) void scatter_geom(
    const int* __restrict__ de,
    const float4* __restrict__ pn,
    const float* __restrict__ nwt,
    unsigned* __restrict__ cnt,
    uint2* __restrict__ srec) {
    const int bm = blockIdx.x & 7;                 // slice (XCD-pinned)
    const int b  = bm >> 1, m = bm & 1;
    const int tid = (blockIdx.x >> 3) * 256 + threadIdx.x;   // 0..65535
    unsigned* cc = cnt + bm * Nn;                  // L2-local slot counters
    uint2* sr = srec + (size_t)bm * Ee;            // 2.56 MB, fits this XCD's L2
    const float4* pnb = pn + b * Nn;
    const i32x4* de4 = (const i32x4*)de;
    const f32x2* nw2 = (const f32x2*)nwt;
    for (int e = tid; e < Ee; e += 65536) {
        i32x4 d4 = __builtin_nontemporal_load(&de4[(size_t)b * Ee + e]);
        f32x2 nw = __builtin_nontemporal_load(&nw2[(size_t)b * Ee + e]);
        int tn = m ? d4.y : d4.x;
        int sn = m ? d4.w : d4.z;
        float4 qt = pnb[tn];
        float4 qs = pnb[sn];
        float dx = qt.x - qs.x, dy = qt.y - qs.y;
        float r2 = dx * dx + dy * dy + 1e-6f;
        float sc = (m ? nw.y : nw.x) * (dx * qs.z + dy * qs.w) / r2;
        unsigned slot = atomicAdd(&cc[tn], 1u);
        sr[slot] = make_uint2((unsigned)tn | ((unsigned)sn << 15), __float_as_uint(sc));
    }
}

// ---------------- kernel 5a (sorted): edge MFMA matvec over sorted records, run-merged atomics
__global__ __launch_bounds__(256, 4) void edge_sorted(
    const float4* __restrict__ pbh4,   // pb fp16 viewed as float4 (4 chunks/row)
    const __half* __restrict__ fTh,
    const uint2* __restrict__ srec,
    const float* __restrict__ wc,
    const float* __restrict__ wsp,
    const float* __restrict__ w0,
    __half* __restrict__ f_out) {
    __shared__ __align__(16) __half spb[4][16 * 64];   // 8192 B
    const int t  = threadIdx.x;
    const int wv = t >> 6;
    const int l  = t & 63;
    const int c  = l & 15;
    const int q  = l >> 4;
    const int mode = q >> 1;
    const unsigned smask2 = mode ? 0x80008000u : 0u;
    const int bm = blockIdx.x & 7;                 // slice = b*2+m (XCD-pinned)
    const int b  = bm >> 1, m = bm & 1;
    const int wid = (blockIdx.x >> 3) * 4 + wv;    // 0..999
    const u32x2* rbase = (const u32x2*)(srec + (size_t)bm * Ee + wid * 320);
    const int pbbase = bm * Nn;
    const int fbase  = b * Nn;

    // loop-invariant B fragments (weights, fp16): B[k=q*8+j][ch]
    half8 bf0, bf1;
    #pragma unroll
    for (int j = 0; j < 8; ++j) {
        int k = q * 8 + j;
        float w0v, w1v;
        if (k < 16) {
            w0v = 2.0f * wc[(c * Kk + k) * Mm + m];
            w1v = 2.0f * wc[((c + 16) * Kk + k) * Mm + m];
        } else {
            w0v = 2.0f * wsp[(c * Kk + (k - 16)) * Mm + m];
            w1v = 2.0f * wsp[((c + 16) * Kk + (k - 16)) * Mm + m];
        }
        bf0[j] = (_Float16)w0v;
        bf1[j] = (_Float16)w1v;
    }
    const float acc00 = w0[c * Mm + m] + 1.0f;
    const float acc01 = w0[(c + 16) * Mm + m] + 1.0f;

    __half* myld = spb[wv];
    const int il = l >> 2, jj4 = l & 3;
    // LDS addresses: phys chunk = logical ^ (row & 7) -> conflict-free b128
    float4* wT = (float4*)(myld + il * 64 + 8 * (jj4 ^ (il & 7)));
    float4* wS = (float4*)(myld + il * 64 + 8 * ((4 | jj4) ^ (il & 7)));
    const int cs = c & 7;
    const float4* rBC = (const float4*)(myld + c * 64 + 8 * ((q & 1) ^ cs));
    const float4* rBS = (const float4*)(myld + c * 64 + 8 * ((2 | (q & 1)) ^ cs));
    const float4* rXX = (const float4*)(myld + c * 64 + 8 * ((4 | q) ^ cs));
    const float4* rYY = (const float4*)(myld + c * 64 + 8 * ((4 | (q ^ 2)) ^ cs));

    const int ceven = ((c & 1) == 0);
    const int choff = ceven ? c : (c + 15);        // pk-atomic halfword offset

    // run-merge state (fp32 accumulation, flush on target change)
    int cur_row = -1;
    float a0 = 0.f, a1 = 0.f;

    // lane l holds record rq*80 + it*16 + ri of this wave's 320-edge range
    const int rq = l >> 4, ri = l & 15;
    u32x2 rc = __builtin_nontemporal_load(&rbase[rq * 80 + ri]);
    float scf = __uint_as_float(rc.y);

    float4 g0, g2;
    float fa[4], fb[4];
    {   // prologue prefetch for (it=0, tau=0)
        int srcR = ((il >> 2) << 4) + (il & 3);
        unsigned px = (unsigned)__shfl((int)rc.x, srcR);
        int tn = px & 32767, sn = (px >> 15) & 32767;
        g0 = pbh4[(size_t)(pbbase + tn) * 4 + jj4];
        g2 = pbh4[(size_t)(pbbase + sn) * 4 + jj4];
        #pragma unroll
        for (int r = 0; r < 4; ++r) {
            unsigned pf = (unsigned)__shfl((int)rc.x, (q << 4) + r);
            int sr = (pf >> 15) & 32767;
            fa[r] = __half2float(fTh[(size_t)(fbase + sr) * CIN + c]);
            fb[r] = __half2float(fTh[(size_t)(fbase + sr) * CIN + c + 16]);
        }
    }

    u32x2 rn;
    for (int it = 0; it < 5; ++it) {
        const bool lastit = (it == 4);
        if (!lastit) rn = __builtin_nontemporal_load(&rbase[rq * 80 + (it + 1) * 16 + ri]);
        #pragma unroll
        for (int tau = 0; tau < 4; ++tau) {
            // ---- 1. commit prefetched pb rows to LDS (swizzled)
            *wT = g0;
            *wS = g2;

            // ---- 2. A-frag: fp16 LDS reads + pk-fp16 math + fp16 MFMA
            union { float4 v; unsigned u[4]; } ubc, ubs, uxx, uyy;
            ubc.v = *rBC; ubs.v = *rBS; uxx.v = *rXX; uyy.v = *rYY;
            union { half8 h8; unsigned u[4]; } af;
            #pragma unroll
            for (int jp = 0; jp < 4; ++jp) {
                unsigned bsbits = ubs.u[jp] ^ smask2;
                __half2 hb = *(__half2*)&ubc.u[jp];
                __half2 hs = *(__half2*)&bsbits;
                __half2 hx = *(__half2*)&uxx.u[jp];
                __half2 hy = *(__half2*)&uyy.u[jp];
                __half2 v  = __hfma2(hb, hx, __hmul2(hs, hy));
                af.u[jp] = *(unsigned*)&v;
            }
            f32x4 zero = {0.f, 0.f, 0.f, 0.f};
            f32x4 d0 = __builtin_amdgcn_mfma_f32_16x16x32_f16(af.h8, bf0, zero, 0, 0, 0);
            f32x4 d1 = __builtin_amdgcn_mfma_f32_16x16x32_f16(af.h8, bf1, zero, 0, 0, 0);

            // ---- 3. epilogue + run-merge (each q-group walks its 80 edges in sorted order)
            #pragma unroll
            for (int r = 0; r < 4; ++r) {
                int srcl = (q << 4) + (tau << 2) + r;
                float sc = __shfl(scf, srcl);
                int row  = (unsigned)__shfl((int)rc.x, srcl) & 32767;
                float v0 = (acc00 + d0[r]) * fa[r] * sc;
                float v1 = (acc01 + d1[r]) * fb[r] * sc;
                // predicate uniform across the 16 c-lanes of this q-group,
                // so the (c, c^1) pk-pair always branches together
                if (row != cur_row) {
                    if (cur_row >= 0) {
                        float n0 = __shfl_xor(a0, 1);
                        float n1 = __shfl_xor(a1, 1);
                        __half2 hv = ceven ? __floats2half2_rn(a0, n0)
                                           : __floats2half2_rn(n1, a1);
                        unsafeAtomicAdd((__half2*)(f_out +
                            (size_t)(fbase + cur_row) * CIN + choff), hv);
                    }
                    cur_row = row; a0 = v0; a1 = v1;
                } else {
                    a0 += v0; a1 += v1;
                }
            }

            // ---- 4. prefetch next tau (pb rows + fT)
            if (tau < 3 || !lastit) {
                const int ntau = (tau == 3) ? 0 : tau + 1;
                const unsigned bx = (tau == 3) ? rn.x : rc.x;
                int srcR = ((il >> 2) << 4) + (ntau << 2) + (il & 3);
                unsigned px = (unsigned)__shfl((int)bx, srcR);
                int tn = px & 32767, sn = (px >> 15) & 32767;
                g0 = pbh4[(size_t)(pbbase + tn) * 4 + jj4];
                g2 = pbh4[(size_t)(pbbase + sn) * 4 + jj4];
                #pragma unroll
                for (int r = 0; r < 4; ++r) {
                    unsigned pf = (unsigned)__shfl((int)bx, (q << 4) + (ntau << 2) + r);
                    int sr = (pf >> 15) & 32767;
                    fa[r] = __half2float(fTh[(size_t)(fbase + sr) * CIN + c]);
                    fb[r] = __half2float(fTh[(size_t)(fbase + sr) * CIN + c + 16]);
                }
            }
        }
        if (!lastit) { rc = rn; scf = __uint_as_float(rc.y); }
    }
    // ---- final flush (cur_row valid: every lane processed 80 edges)
    {
        float n0 = __shfl_xor(a0, 1);
        float n1 = __shfl_xor(a1, 1);
        __half2 hv = ceven ? __floats2half2_rn(a0, n0)
                           : __floats2half2_rn(n1, a1);
        unsafeAtomicAdd((__half2*)(f_out + (size_t)(fbase + cur_row) * CIN + choff), hv);
    }
}

// ---------------- kernel 5b (direct, fallback): unsorted edge scatter
__global__ __launch_bounds__(256, 4) void edge_direct(
    const float4* __restrict__ pbh4,
    const float4* __restrict__ pn,
    const __half* __restrict__ fTh,
    const int4* __restrict__ de4,
    const float* __restrict__ nwt,
    const float* __restrict__ wc,
    const float* __restrict__ wsp,
    const float* __restrict__ w0,
    __half* __restrict__ f_out) {
    __shared__ __align__(16) __half spb[4][16 * 64];
    const int t  = threadIdx.x;
    const int wv = t >> 6;
    const int l  = t & 63;
    const int c  = l & 15;
    const int q  = l >> 4;
    const int mode = q >> 1;
    const unsigned smask2 = mode ? 0x80008000u : 0u;
    const int bm = blockIdx.x & 7;
    const int b  = bm >> 1, m = bm & 1;
    const int wid = (blockIdx.x >> 3) * 4 + wv;
    const int rowoff = (b + m) * Nn;

    half8 bf0, bf1;
    #pragma unroll
    for (int j = 0; j < 8; ++j) {
        int k = q * 8 + j;
        float w0v, w1v;
        if (k < 16) {
            w0v = 2.0f * wc[(c * Kk + k) * Mm + m];
            w1v = 2.0f * wc[((c + 16) * Kk + k) * Mm + m];
        } else {
            w0v = 2.0f * wsp[(c * Kk + (k - 16)) * Mm + m];
            w1v = 2.0f * wsp[((c + 16) * Kk + (k - 16)) * Mm + m];
        }
        bf0[j] = (_Float16)w0v;
        bf1[j] = (_Float16)w1v;
    }
    const float acc00 = w0[c * Mm + m] + 1.0f;
    const float acc01 = w0[(c + 16) * Mm + m] + 1.0f;

    __half* myld = spb[wv];
    const int il = l >> 2, jj4 = l & 3;
    float4* wT = (float4*)(myld + il * 64 + 8 * (jj4 ^ (il & 7)));
    float4* wS = (float4*)(myld + il * 64 + 8 * ((4 | jj4) ^ (il & 7)));
    const int cs = c & 7;
    const float4* rBC = (const float4*)(myld + c * 64 + 8 * ((q & 1) ^ cs));
    const float4* rBS = (const float4*)(myld + c * 64 + 8 * ((2 | (q & 1)) ^ cs));
    const float4* rXX = (const float4*)(myld + c * 64 + 8 * ((4 | q) ^ cs));
    const float4* rYY = (const float4*)(myld + c * 64 + 8 * ((4 | (q ^ 2)) ^ cs));
    const int ceven = ((c & 1) == 0);
    const int choff = ceven ? c : (c + 15);

    float scale; int bt, bs;
    float4 g0, g2;
    float fa[4], fb[4];
    int4  d4n;
    int   btn, bsn;
    float dxn, dyn, nzn, nwn2, nwn;

    int s = wid;
    {
        int e = s * 64 + l;
        int4 d4 = de4[b * Ee + e];
        int tn = m ? d4.y : d4.x;
        int sn = m ? d4.w : d4.z;
        bt = b * Nn + tn;
        bs = b * Nn + sn;
        float4 qt = pn[bt];
        float4 qs = pn[bs];
        float dx = qt.x - qs.x, dy = qt.y - qs.y;
        float r2 = dx * dx + dy * dy + 1e-6f;
        scale = nwt[(b * Ee + e) * Mm + m] * (dx * qs.z + dy * qs.w) / r2;
        int bta = __shfl(bt, il), bsa = __shfl(bs, il);
        g0 = pbh4[(bta + rowoff) * 4 + jj4];
        g2 = pbh4[(bsa + rowoff) * 4 + jj4];
        #pragma unroll
        for (int r = 0; r < 4; ++r) {
            int bsr = __shfl(bs, 4 * q + r);
            fa[r] = __half2float(fTh[bsr * CIN + c]);
            fb[r] = __half2float(fTh[bsr * CIN + c + 16]);
        }
    }

    for (; s < EPB; s += WPB) {
        const bool last = (s + WPB >= EPB);
        #pragma unroll
        for (int tau = 0; tau < 4; ++tau) {
            *wT = g0;
            *wS = g2;
            union { float4 v; unsigned u[4]; } ubc, ubs, uxx, uyy;
            ubc.v = *rBC; ubs.v = *rBS; uxx.v = *rXX; uyy.v = *rYY;
            union { half8 h8; unsigned u[4]; } af;
            #pragma unroll
            for (int jp = 0; jp < 4; ++jp) {
                unsigned bsbits = ubs.u[jp] ^ smask2;
                __half2 hb = *(__half2*)&ubc.u[jp];
                __half2 hs = *(__half2*)&bsbits;
                __half2 hx = *(__half2*)&uxx.u[jp];
                __half2 hy = *(__half2*)&uyy.u[jp];
                __half2 v  = __hfma2(hb, hx, __hmul2(hs, hy));
                af.u[jp] = *(unsigned*)&v;
            }
            f32x4 zero = {0.f, 0.f, 0.f, 0.f};
            f32x4 d0 = __builtin_amdgcn_mfma_f32_16x16x32_f16(af.h8, bf0, zero, 0, 0, 0);
            f32x4 d1 = __builtin_amdgcn_mfma_f32_16x16x32_f16(af.h8, bf1, zero, 0, 0, 0);

            float val0[4], val1[4];
            int   btr[4];
            #pragma unroll
            for (int r = 0; r < 4; ++r) {
                int srcl = tau * 16 + 4 * q + r;
                float sc = __shfl(scale, srcl);
                btr[r]   = __shfl(bt, srcl);
                val0[r] = (acc00 + d0[r]) * fa[r] * sc;
                val1[r] = (acc01 + d1[r]) * fb[r] * sc;
            }

            if (tau == 1 && !last)
                d4n = de4[b * Ee + (s + WPB) * 64 + l];
            if (tau == 2 && !last) {
                int tn = m ? d4n.y : d4n.x;
                int sn = m ? d4n.w : d4n.z;
                btn = b * Nn + tn;
                bsn = b * Nn + sn;
                float4 qt = pn[btn];
                float4 qs = pn[bsn];
                dxn = qt.x - qs.x; dyn = qt.y - qs.y;
                nzn = qs.z; nwn2 = qs.w;
                nwn = nwt[(b * Ee + (s + WPB) * 64 + l) * Mm + m];
            }

            if (tau < 3 || !last) {
                int ntau;
                if (tau == 3) {
                    float r2 = dxn * dxn + dyn * dyn + 1e-6f;
                    scale = nwn * (dxn * nzn + dyn * nwn2) / r2;
                    bt = btn; bs = bsn;
                    ntau = 0;
                } else {
                    ntau = tau + 1;
                }
                int srcA = ntau * 16 + il;
                int bta = __shfl(bt, srcA), bsa = __shfl(bs, srcA);
                g0 = pbh4[(bta + rowoff) * 4 + jj4];
                g2 = pbh4[(bsa + rowoff) * 4 + jj4];
                #pragma unroll
                for (int r = 0; r < 4; ++r) {
                    int bsr = __shfl(bs, ntau * 16 + 4 * q + r);
                    fa[r] = __half2float(fTh[bsr * CIN + c]);
                    fb[r] = __half2float(fTh[bsr * CIN + c + 16]);
                }
            }

            __builtin_amdgcn_sched_barrier(0);
            #pragma unroll
            for (int r = 0; r < 4; ++r) {
                float n0 = __shfl_xor(val0[r], 1);
                float n1 = __shfl_xor(val1[r], 1);
                __half2 hv = ceven ? __floats2half2_rn(val0[r], n0)
                                   : __floats2half2_rn(n1, val1[r]);
                unsafeAtomicAdd((__half2*)(f_out + (size_t)btr[r] * CIN + choff), hv);
            }
        }
    }
}

// ---------------- kernel 6: out[b,o,n] = bias[o] + sum_i wk[o,i] * f_out[b,n,i]
__global__ __launch_bounds__(256) void out_kernel(
    const float4* __restrict__ f_out4,    // fp16 data viewed as float4 (8 halves)
    const float* __restrict__ wk,
    const float* __restrict__ bias,
    float* __restrict__ out) {
    __shared__ float lwk[1024];
    __shared__ float lf[64 * 33];
    int blk  = blockIdx.x;
    int b    = blk / 313;
    int tile = blk % 313;
    int n0   = tile * 64;
    int t    = threadIdx.x;
    #pragma unroll
    for (int r = 0; r < 4; ++r) lwk[r * 256 + t] = wk[r * 256 + t];
    {
        int nl = t >> 2, i8 = t & 3;
        int n  = n0 + nl;
        union { float4 v; __half2 h[4]; } u;
        u.v = (n < Nn) ? f_out4[((size_t)b * Nn + n) * 4 + i8]
                       : make_float4(0, 0, 0, 0);
        float* p = lf + nl * 33 + i8 * 8;
        #pragma unroll
        for (int j = 0; j < 4; ++j) {
            float2 fj = __half22float2(u.h[j]);
            p[2 * j]     = fj.x;
            p[2 * j + 1] = fj.y;
        }
    }
    __syncthreads();
    int nl = t & 63;
    int og = t >> 6;
    int n  = n0 + nl;
    if (n < Nn) {
        #pragma unroll
        for (int r = 0; r < 8; ++r) {
            int o = r * 4 + og;
            float acc = bias[o];
            #pragma unroll
            for (int i = 0; i < 32; ++i) acc += lwk[o * 32 + i] * lf[nl * 33 + i];
            out[(b * COUT + o) * Nn + n] = acc;
        }
    }
}

extern "C" void kernel_launch(void* const* d_in, const int* in_sizes, int n_in,
                              void* d_out, int out_size, void* d_ws, size_t ws_size,
                              hipStream_t stream) {
    const float* f       = (const float*)d_in[0];
    const float* bases_c = (const float*)d_in[1];
    const float* bases_s = (const float*)d_in[2];
    const float* nodes   = (const float*)d_in[4];
    const float* nrm     = (const float*)d_in[5];
    const int*   de      = (const int*)d_in[6];
    const float* nwt     = (const float*)d_in[7];
    const float* wc      = (const float*)d_in[8];
    const float* wsp     = (const float*)d_in[9];
    const float* w0      = (const float*)d_in[10];
    const float* wk      = (const float*)d_in[11];
    const float* bias    = (const float*)d_in[12];
    float* out = (float*)d_out;

    __half*   fT    = (__half*)d_ws;                           // 5.12 MB
    __half*   pb    = fT + 2560000;                            // 10.24 MB
    float4*   pn    = (float4*)(pb + 5120000);                 // 1.28 MB
    __half*   f_out = (__half*)(pn + 80000);                   // 5.12 MB  (ends 21.76 MB)
    unsigned* cnt   = (unsigned*)(f_out + 2560000);            // 0.64 MB
    uint2*    srec  = (uint2*)(cnt + 160000);                  // 20.48 MB (ends 42.88 MB)

    const bool sorted = (ws_size >= (size_t)42880000);

    prep_fused<<<2500, 256, 0, stream>>>(f, (const float4*)bases_c,
                                         (const float4*)bases_s, nodes, nrm,
                                         fT, (float4*)f_out, pb, pn,
                                         sorted ? (uint4*)cnt : (uint4*)nullptr);
    if (sorted) {
        hist_kernel<<<2048, 256, 0, stream>>>(de, cnt);
        scan_kernel<<<8, 1024, 0, stream>>>(cnt);
        scatter_geom<<<2048, 256, 0, stream>>>(de, pn, nwt, cnt, srec);
        edge_sorted<<<2000, 256, 0, stream>>>((const float4*)pb, fT, srec,
                                              wc, wsp, w0, f_out);
    } else {
        edge_direct<<<2000, 256, 0, stream>>>((const float4*)pb, pn, fT,
                                              (const int4*)de, nwt, wc, wsp, w0, f_out);
    }
    out_kernel<<<Bb * 313, 256, 0, stream>>>((const float4*)f_out, wk, bias, out);
}

// Round 5
// 408.550 us; speedup vs baseline: 1.1744x; 1.0455x over previous
//
#include <hip/hip_runtime.h>
#include <hip/hip_fp16.h>

#define Bb 4
#define Nn 20000
#define Ee 320000
#define CIN 32
#define COUT 32
#define Kk 16
#define Mm 2
#define EPB (Ee / 64)   /* 5000 super-iters (64 instances) per (b,m) slice */
#define WPB 1000        /* waves per (b,m): (2000/8) blocks * 4 waves -> exactly 5 iters/wave */

typedef __attribute__((ext_vector_type(8))) _Float16 half8;
typedef __attribute__((ext_vector_type(4))) float f32x4;

// ---------------- kernel 1: prep: transpose f -> fT (fp16); pack pb (fp16), pn; zero f_out2
__global__ __launch_bounds__(256) void prep_fused(
    const float* __restrict__ f,
    const float4* __restrict__ bc4,
    const float4* __restrict__ bs4,
    const float* __restrict__ nodes,
    const float* __restrict__ nrm,
    __half* __restrict__ fT,          // [b][n][32] fp16
    float4* __restrict__ f_outz,      // fp16 accumulator (8 slices) viewed as float4 for zeroing
    __half* __restrict__ pb,          // [(b*2+m)][n][32] fp16: [bc 0..15 | bs 0..15]
    float4* __restrict__ pn) {
    __shared__ float ldsT[32 * 33];
    __shared__ float ldc[32 * 33];
    __shared__ float ldss[32 * 33];
    const int t   = threadIdx.x;
    const int blk = blockIdx.x;            // 2500 blocks
    const int b   = blk / 625;
    const int n0  = (blk % 625) * 32;
    {
        int lane = t & 31, grp = t >> 5;
        #pragma unroll
        for (int r = 0; r < 4; ++r)
            ldsT[(grp + r * 8) * 33 + lane] = f[(b * CIN + grp + r * 8) * Nn + n0 + lane];
        __syncthreads();
        // fp16 write: thread t -> node (t>>3), channels 4*(t&7)..+3 (8B coalesced)
        int nl = t >> 3, c4 = (t & 7) * 4;
        union { short4 s4; __half h[4]; } u;
        #pragma unroll
        for (int j = 0; j < 4; ++j)
            u.h[j] = __float2half(ldsT[(c4 + j) * 33 + nl]);
        *(short4*)(fT + ((size_t)(b * Nn) + n0 + nl) * CIN + c4) = u.s4;
    }
    {
        int nl = t >> 3, j4 = t & 7;
        float4 vc = bc4[(b * Nn + n0 + nl) * 8 + j4];
        float4 vs = bs4[(b * Nn + n0 + nl) * 8 + j4];
        float* pc = ldc + nl * 33 + 4 * j4;
        pc[0] = vc.x; pc[1] = vc.y; pc[2] = vc.z; pc[3] = vc.w;
        float* ps = ldss + nl * 33 + 4 * j4;
        ps[0] = vs.x; ps[1] = vs.y; ps[2] = vs.z; ps[3] = vs.w;
        __syncthreads();
        // pb row (fp16, 32 halves): chunk 0=bc[0..7] 1=bc[8..15] 2=bs[0..7] 3=bs[8..15]
        int m = (t >> 2) & 1, chunk = t & 3;
        const float* src = (chunk < 2 ? ldc : ldss) + nl * 33;
        int k0 = (chunk & 1) * 8;
        union { float4 v; __half h[8]; } o;
        #pragma unroll
        for (int j = 0; j < 8; ++j)
            o.h[j] = __float2half(src[2 * (k0 + j) + m]);
        ((float4*)pb)[(((size_t)(b * 2 + m)) * Nn + n0 + nl) * 4 + chunk] = o.v;
    }
    const int t0 = blk * 256 + t, S = 2500 * 256;
    // f_out2 is 8 slices * Nn*32 halves = 10.24 MB = 640000 float4
    for (int i = t0; i < 640000; i += S) f_outz[i] = make_float4(0, 0, 0, 0);
    for (int i = t0; i < Bb * Nn; i += S) {
        float2 nd = ((const float2*)nodes)[i];
        float2 nv = ((const float2*)nrm)[i];
        pn[i] = make_float4(nd.x, nd.y, nv.x, nv.y);
    }
}

// ---------------- kernel 2: edge scatter, fp16 MFMA matvec, pipelined,
//                  pk-fp16 atomics into a PRIVATE per-(b,m) f_out slice (XCD-local)
__global__ __launch_bounds__(256, 8) void edge_kernel(
    const float4* __restrict__ pbh4,   // pb fp16 viewed as float4 (4 chunks/row)
    const float4* __restrict__ pn,
    const __half* __restrict__ fTh,
    const int4* __restrict__ de4,
    const float* __restrict__ nwt,
    const float* __restrict__ wc,
    const float* __restrict__ wsp,
    const float* __restrict__ w0,
    __half* __restrict__ f_out2) {     // 8 slices of [Nn][32]
    __shared__ __align__(16) __half spb[4][16 * 64];   // 8192 B
    const int t  = threadIdx.x;
    const int wv = t >> 6;
    const int l  = t & 63;
    const int c  = l & 15;
    const int q  = l >> 4;
    const int mode = q >> 1;
    const unsigned smask2 = mode ? 0x80008000u : 0u;   // fp16x2 sign flip
    const int bm = blockIdx.x & 7;                     // slice = b*2+m (XCD-pinned)
    const int b  = bm >> 1, m = bm & 1;
    const int wid = (blockIdx.x >> 3) * 4 + wv;        // 0..999
    const int rowoff = (b + m) * Nn;                   // bt -> pb/f_out2 slice row base add

    // loop-invariant B fragments (weights, fp16): B[k=q*8+j][ch]
    half8 bf0, bf1;
    #pragma unroll
    for (int j = 0; j < 8; ++j) {
        int k = q * 8 + j;
        float w0v, w1v;
        if (k < 16) {
            w0v = 2.0f * wc[(c * Kk + k) * Mm + m];
            w1v = 2.0f * wc[((c + 16) * Kk + k) * Mm + m];
        } else {
            w0v = 2.0f * wsp[(c * Kk + (k - 16)) * Mm + m];
            w1v = 2.0f * wsp[((c + 16) * Kk + (k - 16)) * Mm + m];
        }
        bf0[j] = (_Float16)w0v;
        bf1[j] = (_Float16)w1v;
    }
    const float acc00 = w0[c * Mm + m] + 1.0f;
    const float acc01 = w0[(c + 16) * Mm + m] + 1.0f;

    __half* myld = spb[wv];
    const int il = l >> 2, jj4 = l & 3;
    const int ceven = ((c & 1) == 0);
    const int choff = ceven ? c : (c + 15);           // pk-atomic halfword offset

    // LDS addresses (loop-invariant): phys chunk = logical ^ (row & 7)
    float4* wT = (float4*)(myld + il * 64 + 8 * (jj4 ^ (il & 7)));
    float4* wS = (float4*)(myld + il * 64 + 8 * ((4 | jj4) ^ (il & 7)));
    const int cs = c & 7;
    const float4* rBC = (const float4*)(myld + c * 64 + 8 * ((q & 1) ^ cs));
    const float4* rBS = (const float4*)(myld + c * 64 + 8 * ((2 | (q & 1)) ^ cs));
    const float4* rXX = (const float4*)(myld + c * 64 + 8 * ((4 | q) ^ cs));
    const float4* rYY = (const float4*)(myld + c * 64 + 8 * ((4 | (q ^ 2)) ^ cs));

    // pipeline state
    float scale; int bt, bs;
    float4 g0, g2;
    float fa[4], fb[4];
    int4  d4n;
    int   btn, bsn;
    float dxn, dyn, nzn, nwn2, nwn;

    int s = wid;
    {
        int e = s * 64 + l;
        int4 d4 = de4[b * Ee + e];
        int tn = m ? d4.y : d4.x;
        int sn = m ? d4.w : d4.z;
        bt = b * Nn + tn;
        bs = b * Nn + sn;
        float4 qt = pn[bt];
        float4 qs = pn[bs];
        float dx = qt.x - qs.x, dy = qt.y - qs.y;
        float r2 = dx * dx + dy * dy + 1e-6f;
        scale = nwt[(b * Ee + e) * Mm + m] * (dx * qs.z + dy * qs.w) / r2;
        int bta = __shfl(bt, il), bsa = __shfl(bs, il);
        g0 = pbh4[(bta + rowoff) * 4 + jj4];
        g2 = pbh4[(bsa + rowoff) * 4 + jj4];
        #pragma unroll
        for (int r = 0; r < 4; ++r) {
            int bsr = __shfl(bs, 4 * q + r);
            fa[r] = __half2float(fTh[bsr * CIN + c]);
            fb[r] = __half2float(fTh[bsr * CIN + c + 16]);
        }
    }

    for (; s < EPB; s += WPB) {
        const bool last = (s + WPB >= EPB);
        #pragma unroll
        for (int tau = 0; tau < 4; ++tau) {
            // ---- 1. commit prefetched fp16 pb rows to LDS (swizzled)
            *wT = g0;
            *wS = g2;

            // ---- 2. A-frag: fp16 LDS reads + pk-fp16 math + fp16 MFMA
            union { float4 v; unsigned u[4]; } ubc, ubs, uxx, uyy;
            ubc.v = *rBC; ubs.v = *rBS; uxx.v = *rXX; uyy.v = *rYY;
            union { half8 h8; unsigned u[4]; } af;
            #pragma unroll
            for (int jp = 0; jp < 4; ++jp) {
                unsigned bsbits = ubs.u[jp] ^ smask2;
                __half2 hb = *(__half2*)&ubc.u[jp];
                __half2 hs = *(__half2*)&bsbits;
                __half2 hx = *(__half2*)&uxx.u[jp];
                __half2 hy = *(__half2*)&uyy.u[jp];
                __half2 v  = __hfma2(hb, hx, __hmul2(hs, hy));
                af.u[jp] = *(unsigned*)&v;
            }
            f32x4 zero = {0.f, 0.f, 0.f, 0.f};
            f32x4 d0 = __builtin_amdgcn_mfma_f32_16x16x32_f16(af.h8, bf0, zero, 0, 0, 0);
            f32x4 d1 = __builtin_amdgcn_mfma_f32_16x16x32_f16(af.h8, bf1, zero, 0, 0, 0);

            // ---- 3. epilogue values (consume fa/fb BEFORE prefetch overwrites)
            float val0[4], val1[4];
            int   btr[4];
            #pragma unroll
            for (int r = 0; r < 4; ++r) {
                int srcl = tau * 16 + 4 * q + r;
                float sc = __shfl(scale, srcl);
                btr[r]   = __shfl(bt, srcl);
                val0[r] = (acc00 + d0[r]) * fa[r] * sc;
                val1[r] = (acc01 + d1[r]) * fb[r] * sc;
            }

            // ---- 4. geometry pipeline for next super-iter
            if (tau == 1 && !last)
                d4n = de4[b * Ee + (s + WPB) * 64 + l];
            if (tau == 2 && !last) {
                int tn = m ? d4n.y : d4n.x;
                int sn = m ? d4n.w : d4n.z;
                btn = b * Nn + tn;
                bsn = b * Nn + sn;
                float4 qt = pn[btn];
                float4 qs = pn[bsn];
                dxn = qt.x - qs.x; dyn = qt.y - qs.y;
                nzn = qs.z; nwn2 = qs.w;
                nwn = nwt[(b * Ee + (s + WPB) * 64 + l) * Mm + m];
            }

            // ---- 5. prefetch next tile (pb rows + fT) BEFORE atomics
            if (tau < 3 || !last) {
                int ntau;
                if (tau == 3) {
                    float r2 = dxn * dxn + dyn * dyn + 1e-6f;
                    scale = nwn * (dxn * nzn + dyn * nwn2) / r2;
                    bt = btn; bs = bsn;
                    ntau = 0;
                } else {
                    ntau = tau + 1;
                }
                int srcA = ntau * 16 + il;
                int bta = __shfl(bt, srcA), bsa = __shfl(bs, srcA);
                g0 = pbh4[(bta + rowoff) * 4 + jj4];
                g2 = pbh4[(bsa + rowoff) * 4 + jj4];
                #pragma unroll
                for (int r = 0; r < 4; ++r) {
                    int bsr = __shfl(bs, ntau * 16 + 4 * q + r);
                    fa[r] = __half2float(fTh[bsr * CIN + c]);
                    fb[r] = __half2float(fTh[bsr * CIN + c + 16]);
                }
            }

            // ---- 6. pk-fp16 atomics last, into the slice-private region (XCD-local)
            __builtin_amdgcn_sched_barrier(0);
            #pragma unroll
            for (int r = 0; r < 4; ++r) {
                float n0 = __shfl_xor(val0[r], 1);   // neighbor's ch c^1 value
                float n1 = __shfl_xor(val1[r], 1);   // neighbor's ch (c^1)+16 value
                __half2 hv = ceven ? __floats2half2_rn(val0[r], n0)
                                   : __floats2half2_rn(n1, val1[r]);
                unsafeAtomicAdd((__half2*)(f_out2 +
                    (size_t)(btr[r] + rowoff) * CIN + choff), hv);
            }
        }
    }
}

// ---------------- kernel 3: out[b,o,n] = bias[o] + sum_i wk[o,i] *
//                  (f_out2[2b][n,i] + f_out2[2b+1][n,i])
__global__ __launch_bounds__(256) void out_kernel(
    const float4* __restrict__ f_out4,    // 8 slices of fp16 data viewed as float4
    const float* __restrict__ wk,
    const float* __restrict__ bias,
    float* __restrict__ out) {
    __shared__ float lwk[1024];
    __shared__ float lf[64 * 33];
    int blk  = blockIdx.x;
    int b    = blk / 313;
    int tile = blk % 313;
    int n0   = tile * 64;
    int t    = threadIdx.x;
    #pragma unroll
    for (int r = 0; r < 4; ++r) lwk[r * 256 + t] = wk[r * 256 + t];
    {
        // 64 nodes x 32 ch x 2 slices: sum the two m-copies while staging
        int nl = t >> 2, i8 = t & 3;
        int n  = n0 + nl;
        union { float4 v; __half2 h[4]; } u0, u1;
        if (n < Nn) {
            u0.v = f_out4[((size_t)(2 * b) * Nn + n) * 4 + i8];
            u1.v = f_out4[((size_t)(2 * b + 1) * Nn + n) * 4 + i8];
        } else {
            u0.v = make_float4(0, 0, 0, 0);
            u1.v = make_float4(0, 0, 0, 0);
        }
        float* p = lf + nl * 33 + i8 * 8;
        #pragma unroll
        for (int j = 0; j < 4; ++j) {
            float2 f0 = __half22float2(u0.h[j]);
            float2 f1 = __half22float2(u1.h[j]);
            p[2 * j]     = f0.x + f1.x;
            p[2 * j + 1] = f0.y + f1.y;
        }
    }
    __syncthreads();
    int nl = t & 63;
    int og = t >> 6;
    int n  = n0 + nl;
    if (n < Nn) {
        #pragma unroll
        for (int r = 0; r < 8; ++r) {
            int o = r * 4 + og;
            float acc = bias[o];
            #pragma unroll
            for (int i = 0; i < 32; ++i) acc += lwk[o * 32 + i] * lf[nl * 33 + i];
            out[(b * COUT + o) * Nn + n] = acc;
        }
    }
}

extern "C" void kernel_launch(void* const* d_in, const int* in_sizes, int n_in,
                              void* d_out, int out_size, void* d_ws, size_t ws_size,
                              hipStream_t stream) {
    const float* f       = (const float*)d_in[0];
    const float* bases_c = (const float*)d_in[1];
    const float* bases_s = (const float*)d_in[2];
    const float* nodes   = (const float*)d_in[4];
    const float* nrm     = (const float*)d_in[5];
    const int*   de      = (const int*)d_in[6];
    const float* nwt     = (const float*)d_in[7];
    const float* wc      = (const float*)d_in[8];
    const float* wsp     = (const float*)d_in[9];
    const float* w0      = (const float*)d_in[10];
    const float* wk      = (const float*)d_in[11];
    const float* bias    = (const float*)d_in[12];
    float* out = (float*)d_out;

    __half* fT     = (__half*)d_ws;                            // 5.12 MB
    __half* pb     = fT + 2560000;                             // 10.24 MB
    float4* pn     = (float4*)(pb + 5120000);                  // 1.28 MB
    __half* f_out2 = (__half*)(pn + 80000);                    // 8 x 1.28 MB = 10.24 MB (ends 26.88 MB)

    prep_fused<<<2500, 256, 0, stream>>>(f, (const float4*)bases_c,
                                         (const float4*)bases_s, nodes, nrm,
                                         fT, (float4*)f_out2, pb, pn);
    edge_kernel<<<2000, 256, 0, stream>>>((const float4*)pb, pn, fT,
                                          (const int4*)de, nwt, wc, wsp, w0, f_out2);
    out_kernel<<<Bb * 313, 256, 0, stream>>>((const float4*)f_out2, wk, bias, out);
}

// Round 6
// 268.452 us; speedup vs baseline: 1.7873x; 1.5219x over previous
//
#include <hip/hip_runtime.h>
#include <hip/hip_fp16.h>

#define Bb 4
#define Nn 20000
#define Ee 320000
#define CIN 32
#define COUT 32
#define Kk 16
#define Mm 2
#define EPB (Ee / 64)   /* 5000 super-iters (64 instances) per (b,m) slice */
#define WPB 1000        /* waves per (b,m): (2000/8) blocks * 4 waves -> exactly 5 iters/wave */

typedef __attribute__((ext_vector_type(8))) _Float16 half8;
typedef __attribute__((ext_vector_type(4))) float f32x4;

// ---------------- kernel 1: prep: transpose f -> fT (fp16); pack pb (fp16), pn; zero f_out2
__global__ __launch_bounds__(256) void prep_fused(
    const float* __restrict__ f,
    const float4* __restrict__ bc4,
    const float4* __restrict__ bs4,
    const float* __restrict__ nodes,
    const float* __restrict__ nrm,
    __half* __restrict__ fT,          // [b][n][32] fp16
    float4* __restrict__ f_outz,      // fp16 accumulator (8 slices) viewed as float4 for zeroing
    __half* __restrict__ pb,          // [(b*2+m)][n][32] fp16: [bc 0..15 | bs 0..15]
    float4* __restrict__ pn) {
    __shared__ float ldsT[32 * 33];
    __shared__ float ldc[32 * 33];
    __shared__ float ldss[32 * 33];
    const int t   = threadIdx.x;
    const int blk = blockIdx.x;            // 2500 blocks
    const int b   = blk / 625;
    const int n0  = (blk % 625) * 32;
    {
        int lane = t & 31, grp = t >> 5;
        #pragma unroll
        for (int r = 0; r < 4; ++r)
            ldsT[(grp + r * 8) * 33 + lane] = f[(b * CIN + grp + r * 8) * Nn + n0 + lane];
        __syncthreads();
        // fp16 write: thread t -> node (t>>3), channels 4*(t&7)..+3 (8B coalesced)
        int nl = t >> 3, c4 = (t & 7) * 4;
        union { short4 s4; __half h[4]; } u;
        #pragma unroll
        for (int j = 0; j < 4; ++j)
            u.h[j] = __float2half(ldsT[(c4 + j) * 33 + nl]);
        *(short4*)(fT + ((size_t)(b * Nn) + n0 + nl) * CIN + c4) = u.s4;
    }
    {
        int nl = t >> 3, j4 = t & 7;
        float4 vc = bc4[(b * Nn + n0 + nl) * 8 + j4];
        float4 vs = bs4[(b * Nn + n0 + nl) * 8 + j4];
        float* pc = ldc + nl * 33 + 4 * j4;
        pc[0] = vc.x; pc[1] = vc.y; pc[2] = vc.z; pc[3] = vc.w;
        float* ps = ldss + nl * 33 + 4 * j4;
        ps[0] = vs.x; ps[1] = vs.y; ps[2] = vs.z; ps[3] = vs.w;
        __syncthreads();
        // pb row (fp16, 32 halves): chunk 0=bc[0..7] 1=bc[8..15] 2=bs[0..7] 3=bs[8..15]
        int m = (t >> 2) & 1, chunk = t & 3;
        const float* src = (chunk < 2 ? ldc : ldss) + nl * 33;
        int k0 = (chunk & 1) * 8;
        union { float4 v; __half h[8]; } o;
        #pragma unroll
        for (int j = 0; j < 8; ++j)
            o.h[j] = __float2half(src[2 * (k0 + j) + m]);
        ((float4*)pb)[(((size_t)(b * 2 + m)) * Nn + n0 + nl) * 4 + chunk] = o.v;
    }
    const int t0 = blk * 256 + t, S = 2500 * 256;
    // f_out2 is 8 slices * Nn*32 halves = 10.24 MB = 640000 float4
    for (int i = t0; i < 640000; i += S) f_outz[i] = make_float4(0, 0, 0, 0);
    for (int i = t0; i < Bb * Nn; i += S) {
        float2 nd = ((const float2*)nodes)[i];
        float2 nv = ((const float2*)nrm)[i];
        pn[i] = make_float4(nd.x, nd.y, nv.x, nv.y);
    }
}

// ---------------- kernel 2: edge scatter, fp16 MFMA matvec, pipelined,
//                  pk-fp16 atomics into a PRIVATE per-(b,m) f_out slice (XCD-local)
//                  launch_bounds (256,4): 56 VGPR, NO SPILLS (R5's (256,8) spilled: 294us)
__global__ __launch_bounds__(256, 4) void edge_kernel(
    const float4* __restrict__ pbh4,   // pb fp16 viewed as float4 (4 chunks/row)
    const float4* __restrict__ pn,
    const __half* __restrict__ fTh,
    const int4* __restrict__ de4,
    const float* __restrict__ nwt,
    const float* __restrict__ wc,
    const float* __restrict__ wsp,
    const float* __restrict__ w0,
    __half* __restrict__ f_out2) {     // 8 slices of [Nn][32]
    __shared__ __align__(16) __half spb[4][16 * 64];   // 8192 B
    const int t  = threadIdx.x;
    const int wv = t >> 6;
    const int l  = t & 63;
    const int c  = l & 15;
    const int q  = l >> 4;
    const int mode = q >> 1;
    const unsigned smask2 = mode ? 0x80008000u : 0u;   // fp16x2 sign flip
    const int bm = blockIdx.x & 7;                     // slice = b*2+m (XCD-pinned)
    const int b  = bm >> 1, m = bm & 1;
    const int wid = (blockIdx.x >> 3) * 4 + wv;        // 0..999
    const int rowoff = (b + m) * Nn;                   // bt -> pb/f_out2 slice row base add

    // loop-invariant B fragments (weights, fp16): B[k=q*8+j][ch]
    half8 bf0, bf1;
    #pragma unroll
    for (int j = 0; j < 8; ++j) {
        int k = q * 8 + j;
        float w0v, w1v;
        if (k < 16) {
            w0v = 2.0f * wc[(c * Kk + k) * Mm + m];
            w1v = 2.0f * wc[((c + 16) * Kk + k) * Mm + m];
        } else {
            w0v = 2.0f * wsp[(c * Kk + (k - 16)) * Mm + m];
            w1v = 2.0f * wsp[((c + 16) * Kk + (k - 16)) * Mm + m];
        }
        bf0[j] = (_Float16)w0v;
        bf1[j] = (_Float16)w1v;
    }
    const float acc00 = w0[c * Mm + m] + 1.0f;
    const float acc01 = w0[(c + 16) * Mm + m] + 1.0f;

    __half* myld = spb[wv];
    const int il = l >> 2, jj4 = l & 3;
    const int ceven = ((c & 1) == 0);
    const int choff = ceven ? c : (c + 15);           // pk-atomic halfword offset

    // LDS addresses (loop-invariant): phys chunk = logical ^ (row & 7)
    float4* wT = (float4*)(myld + il * 64 + 8 * (jj4 ^ (il & 7)));
    float4* wS = (float4*)(myld + il * 64 + 8 * ((4 | jj4) ^ (il & 7)));
    const int cs = c & 7;
    const float4* rBC = (const float4*)(myld + c * 64 + 8 * ((q & 1) ^ cs));
    const float4* rBS = (const float4*)(myld + c * 64 + 8 * ((2 | (q & 1)) ^ cs));
    const float4* rXX = (const float4*)(myld + c * 64 + 8 * ((4 | q) ^ cs));
    const float4* rYY = (const float4*)(myld + c * 64 + 8 * ((4 | (q ^ 2)) ^ cs));

    // pipeline state
    float scale; int bt, bs;
    float4 g0, g2;
    float fa[4], fb[4];
    int4  d4n;
    int   btn, bsn;
    float dxn, dyn, nzn, nwn2, nwn;

    int s = wid;
    {
        int e = s * 64 + l;
        int4 d4 = de4[b * Ee + e];
        int tn = m ? d4.y : d4.x;
        int sn = m ? d4.w : d4.z;
        bt = b * Nn + tn;
        bs = b * Nn + sn;
        float4 qt = pn[bt];
        float4 qs = pn[bs];
        float dx = qt.x - qs.x, dy = qt.y - qs.y;
        float r2 = dx * dx + dy * dy + 1e-6f;
        scale = nwt[(b * Ee + e) * Mm + m] * (dx * qs.z + dy * qs.w) / r2;
        int bta = __shfl(bt, il), bsa = __shfl(bs, il);
        g0 = pbh4[(bta + rowoff) * 4 + jj4];
        g2 = pbh4[(bsa + rowoff) * 4 + jj4];
        #pragma unroll
        for (int r = 0; r < 4; ++r) {
            int bsr = __shfl(bs, 4 * q + r);
            fa[r] = __half2float(fTh[bsr * CIN + c]);
            fb[r] = __half2float(fTh[bsr * CIN + c + 16]);
        }
    }

    for (; s < EPB; s += WPB) {
        const bool last = (s + WPB >= EPB);
        #pragma unroll
        for (int tau = 0; tau < 4; ++tau) {
            // ---- 1. commit prefetched fp16 pb rows to LDS (swizzled)
            *wT = g0;
            *wS = g2;

            // ---- 2. A-frag: fp16 LDS reads + pk-fp16 math + fp16 MFMA
            union { float4 v; unsigned u[4]; } ubc, ubs, uxx, uyy;
            ubc.v = *rBC; ubs.v = *rBS; uxx.v = *rXX; uyy.v = *rYY;
            union { half8 h8; unsigned u[4]; } af;
            #pragma unroll
            for (int jp = 0; jp < 4; ++jp) {
                unsigned bsbits = ubs.u[jp] ^ smask2;
                __half2 hb = *(__half2*)&ubc.u[jp];
                __half2 hs = *(__half2*)&bsbits;
                __half2 hx = *(__half2*)&uxx.u[jp];
                __half2 hy = *(__half2*)&uyy.u[jp];
                __half2 v  = __hfma2(hb, hx, __hmul2(hs, hy));
                af.u[jp] = *(unsigned*)&v;
            }
            f32x4 zero = {0.f, 0.f, 0.f, 0.f};
            f32x4 d0 = __builtin_amdgcn_mfma_f32_16x16x32_f16(af.h8, bf0, zero, 0, 0, 0);
            f32x4 d1 = __builtin_amdgcn_mfma_f32_16x16x32_f16(af.h8, bf1, zero, 0, 0, 0);

            // ---- 3. epilogue values (consume fa/fb BEFORE prefetch overwrites)
            float val0[4], val1[4];
            int   btr[4];
            #pragma unroll
            for (int r = 0; r < 4; ++r) {
                int srcl = tau * 16 + 4 * q + r;
                float sc = __shfl(scale, srcl);
                btr[r]   = __shfl(bt, srcl);
                val0[r] = (acc00 + d0[r]) * fa[r] * sc;
                val1[r] = (acc01 + d1[r]) * fb[r] * sc;
            }

            // ---- 4. geometry pipeline for next super-iter
            if (tau == 1 && !last)
                d4n = de4[b * Ee + (s + WPB) * 64 + l];
            if (tau == 2 && !last) {
                int tn = m ? d4n.y : d4n.x;
                int sn = m ? d4n.w : d4n.z;
                btn = b * Nn + tn;
                bsn = b * Nn + sn;
                float4 qt = pn[btn];
                float4 qs = pn[bsn];
                dxn = qt.x - qs.x; dyn = qt.y - qs.y;
                nzn = qs.z; nwn2 = qs.w;
                nwn = nwt[(b * Ee + (s + WPB) * 64 + l) * Mm + m];
            }

            // ---- 5. prefetch next tile (pb rows + fT) BEFORE atomics
            if (tau < 3 || !last) {
                int ntau;
                if (tau == 3) {
                    float r2 = dxn * dxn + dyn * dyn + 1e-6f;
                    scale = nwn * (dxn * nzn + dyn * nwn2) / r2;
                    bt = btn; bs = bsn;
                    ntau = 0;
                } else {
                    ntau = tau + 1;
                }
                int srcA = ntau * 16 + il;
                int bta = __shfl(bt, srcA), bsa = __shfl(bs, srcA);
                g0 = pbh4[(bta + rowoff) * 4 + jj4];
                g2 = pbh4[(bsa + rowoff) * 4 + jj4];
                #pragma unroll
                for (int r = 0; r < 4; ++r) {
                    int bsr = __shfl(bs, ntau * 16 + 4 * q + r);
                    fa[r] = __half2float(fTh[bsr * CIN + c]);
                    fb[r] = __half2float(fTh[bsr * CIN + c + 16]);
                }
            }

            // ---- 6. pk-fp16 atomics last, into the slice-private region (XCD-local)
            __builtin_amdgcn_sched_barrier(0);
            #pragma unroll
            for (int r = 0; r < 4; ++r) {
                float n0 = __shfl_xor(val0[r], 1);   // neighbor's ch c^1 value
                float n1 = __shfl_xor(val1[r], 1);   // neighbor's ch (c^1)+16 value
                __half2 hv = ceven ? __floats2half2_rn(val0[r], n0)
                                   : __floats2half2_rn(n1, val1[r]);
                unsafeAtomicAdd((__half2*)(f_out2 +
                    (size_t)(btr[r] + rowoff) * CIN + choff), hv);
            }
        }
    }
}

// ---------------- kernel 3: out[b,o,n] = bias[o] + sum_i wk[o,i] *
//                  (f_out2[2b][n,i] + f_out2[2b+1][n,i])
__global__ __launch_bounds__(256) void out_kernel(
    const float4* __restrict__ f_out4,    // 8 slices of fp16 data viewed as float4
    const float* __restrict__ wk,
    const float* __restrict__ bias,
    float* __restrict__ out) {
    __shared__ float lwk[1024];
    __shared__ float lf[64 * 33];
    int blk  = blockIdx.x;
    int b    = blk / 313;
    int tile = blk % 313;
    int n0   = tile * 64;
    int t    = threadIdx.x;
    #pragma unroll
    for (int r = 0; r < 4; ++r) lwk[r * 256 + t] = wk[r * 256 + t];
    {
        // 64 nodes x 32 ch x 2 slices: sum the two m-copies while staging
        int nl = t >> 2, i8 = t & 3;
        int n  = n0 + nl;
        union { float4 v; __half2 h[4]; } u0, u1;
        if (n < Nn) {
            u0.v = f_out4[((size_t)(2 * b) * Nn + n) * 4 + i8];
            u1.v = f_out4[((size_t)(2 * b + 1) * Nn + n) * 4 + i8];
        } else {
            u0.v = make_float4(0, 0, 0, 0);
            u1.v = make_float4(0, 0, 0, 0);
        }
        float* p = lf + nl * 33 + i8 * 8;
        #pragma unroll
        for (int j = 0; j < 4; ++j) {
            float2 f0 = __half22float2(u0.h[j]);
            float2 f1 = __half22float2(u1.h[j]);
            p[2 * j]     = f0.x + f1.x;
            p[2 * j + 1] = f0.y + f1.y;
        }
    }
    __syncthreads();
    int nl = t & 63;
    int og = t >> 6;
    int n  = n0 + nl;
    if (n < Nn) {
        #pragma unroll
        for (int r = 0; r < 8; ++r) {
            int o = r * 4 + og;
            float acc = bias[o];
            #pragma unroll
            for (int i = 0; i < 32; ++i) acc += lwk[o * 32 + i] * lf[nl * 33 + i];
            out[(b * COUT + o) * Nn + n] = acc;
        }
    }
}

extern "C" void kernel_launch(void* const* d_in, const int* in_sizes, int n_in,
                              void* d_out, int out_size, void* d_ws, size_t ws_size,
                              hipStream_t stream) {
    const float* f       = (const float*)d_in[0];
    const float* bases_c = (const float*)d_in[1];
    const float* bases_s = (const float*)d_in[2];
    const float* nodes   = (const float*)d_in[4];
    const float* nrm     = (const float*)d_in[5];
    const int*   de      = (const int*)d_in[6];
    const float* nwt     = (const float*)d_in[7];
    const float* wc      = (const float*)d_in[8];
    const float* wsp     = (const float*)d_in[9];
    const float* w0      = (const float*)d_in[10];
    const float* wk      = (const float*)d_in[11];
    const float* bias    = (const float*)d_in[12];
    float* out = (float*)d_out;

    __half* fT     = (__half*)d_ws;                            // 5.12 MB
    __half* pb     = fT + 2560000;                             // 10.24 MB
    float4* pn     = (float4*)(pb + 5120000);                  // 1.28 MB
    __half* f_out2 = (__half*)(pn + 80000);                    // 8 x 1.28 MB = 10.24 MB (ends 26.88 MB)

    prep_fused<<<2500, 256, 0, stream>>>(f, (const float4*)bases_c,
                                         (const float4*)bases_s, nodes, nrm,
                                         fT, (float4*)f_out2, pb, pn);
    edge_kernel<<<2000, 256, 0, stream>>>((const float4*)pb, pn, fT,
                                          (const int4*)de, nwt, wc, wsp, w0, f_out2);
    out_kernel<<<Bb * 313, 256, 0, stream>>>((const float4*)f_out2, wk, bias, out);
}